// Round 13
// baseline (268.309 us; speedup 1.0000x reference)
//
#include <hip/hip_runtime.h>
#include <hip/hip_bf16.h>

#define N_NODESC 50000
#define N_EDGESC 1600000
#define NGC 1024
#define NPC 8
#define NBIN 196          // dst>>8 buckets (256 nodes each)
#define NBLKE 391         // edge chunks of 4096

typedef __attribute__((ext_vector_type(8))) short bf16x8;
typedef __attribute__((ext_vector_type(4))) float f32x4;

__device__ inline ushort f2bf(float f) {
  union { float f; uint u; } v; v.f = f;
  uint u = v.u;
  u += 0x7FFF + ((u >> 16) & 1);
  return (ushort)(u >> 16);
}
__device__ inline float bflo(uint u) {
  union { uint u; float f; } v; v.u = u << 16; return v.f;
}
__device__ inline float bfhi(uint u) {
  union { uint u; float f; } v; v.u = u & 0xFFFF0000u; return v.f;
}
__device__ inline float bfu(ushort u) {
  union { uint u; float f; } v; v.u = (uint)u << 16; return v.f;
}

// ---------------- fused prep: weights + features + histogram + counts ------
__global__ __launch_bounds__(256) void megaprep(
    const float* __restrict__ qa1w, const float* __restrict__ qa2w,
    const float* __restrict__ lin1w, const float* __restrict__ lin2w,
    ushort* __restrict__ qe1, ushort* __restrict__ qe2,
    ushort* __restrict__ l1w, ushort* __restrict__ l2w,
    const int* __restrict__ x, const float* __restrict__ e24,
    const float* __restrict__ e72, ushort* __restrict__ feat,
    const int* __restrict__ dst, int* __restrict__ bh,
    const int* __restrict__ batch, float* __restrict__ cntf) {
  int bid = blockIdx.x, t = threadIdx.x;
  if (bid < 256) {
    const float* qw = (bid < 128) ? qa1w : qa2w;
    ushort* eff = (bid < 128) ? qe1 : qe2;
    int k = (bid & 127) * 2 + (t >> 7);
    int j = t & 127;
    const float* r = qw + (size_t)k * 256;
    float v;
    if (j < 64) v = r[j] + r[128 + j] + r[192 + j];
    else { int j2 = j - 64; v = r[64 + j2] + r[128 + j2] + 2.0f * r[192 + j2]; }
    eff[(size_t)k * 128 + j] = f2bf(v);
  } else if (bid < 304) {
    int i = (bid - 256) * 256 + t;  // < 12288 = 128*96
    int r = i / 96, c = i - r * 96;
    l1w[i] = (c < 68) ? f2bf(lin1w[(size_t)r * 68 + c]) : (ushort)0;
  } else if (bid < 432) {
    int r = bid - 304;
    l2w[(size_t)r * 256 + t] = f2bf(lin2w[(size_t)r * 256 + t]);
  } else if (bid < 1456) {
    const int stride = 1024 * 256;
    for (int i = (bid - 432) * 256 + t; i < N_NODESC * 96; i += stride) {
      int n = i / 96, tt = i - n * 96;
      float v = 0.f;
      if (tt < 4) v = (float)x[n * 4 + tt];
      else if (tt < 36) { int kk = tt - 4;  int f = kk >> 3, c = kk & 7; v = e24[(x[n * 4 + f] % 24) * 8 + c]; }
      else if (tt < 68) { int kk = tt - 36; int f = kk >> 3, c = kk & 7; v = e72[(x[n * 4 + f] % 72) * 8 + c]; }
      feat[i] = f2bf(v);
    }
  } else if (bid < 1847) {
    __shared__ int hist[NBIN];
    int blk = bid - 1456;
    if (t < NBIN) hist[t] = 0;
    __syncthreads();
    int base = blk * 4096;
#pragma unroll
    for (int i = 0; i < 16; ++i) {
      int idx = base + i * 256 + t;
      if (idx < N_EDGESC) atomicAdd(&hist[dst[idx] >> 8], 1);
    }
    __syncthreads();
    if (t < NBIN) bh[(size_t)t * NBLKE + blk] = hist[t];
  } else {
    // per-graph node counts (batch sorted)
    for (int gg = t; gg < NGC; gg += 256) {
      int lo = 0, hi = N_NODESC;
      while (lo < hi) { int mid = (lo + hi) >> 1; if (batch[mid] < gg) lo = mid + 1; else hi = mid; }
      int beg = lo;
      hi = N_NODESC;
      while (lo < hi) { int mid = (lo + hi) >> 1; if (batch[mid] < gg + 1) lo = mid + 1; else hi = mid; }
      cntf[gg] = fmaxf((float)(lo - beg), 1.0f);
    }
  }
}

// ---------------- CSR: per-bin scan ----------------
__global__ __launch_bounds__(64) void csr_scan_bins(int* __restrict__ bh, int* __restrict__ bt) {
  int bin = blockIdx.x;
  int lane = threadIdx.x;
  int carry = 0;
  int* row = bh + (size_t)bin * NBLKE;
  for (int c = 0; c < NBLKE; c += 64) {
    int j = c + lane;
    int v = (j < NBLKE) ? row[j] : 0;
    int incl = v;
#pragma unroll
    for (int off = 1; off < 64; off <<= 1) {
      int u = __shfl_up(incl, off, 64);
      if (lane >= off) incl += u;
    }
    if (j < NBLKE) row[j] = carry + incl - v;
    carry += __shfl(incl, 63, 64);
  }
  if (lane == 0) bt[bin] = carry;
}

// ---------------- shared GEMM body (W staged in swizzled LDS) ---------------
template <int K>
__device__ __forceinline__ void gemm_body(ushort* ws, int bx, int by,
    const ushort* __restrict__ A, const ushort* __restrict__ W,
    const float* __restrict__ bias, ushort* __restrict__ C,
    int M, int NC, int relu) {
  int tid = threadIdx.x;
  int lane = tid & 63;
  int wv = tid >> 6;
  int rbase = bx * 128 + wv * 32;
  int colt = by * 128;
  int r16 = lane & 15;
  int kg = (lane >> 4) * 8;

  const char* wt = (const char*)(W + (size_t)colt * K);
#pragma unroll
  for (int i = 0; i < K / 16; ++i) {
    int o = (i * 256 + tid) * 16;
    int col = o / (2 * K);
    int sw = o ^ ((col & 7) << 4);
    *(bf16x8*)((char*)ws + sw) = *(const bf16x8*)(wt + o);
  }
  __syncthreads();

  f32x4 acc[2][8];
#pragma unroll
  for (int m = 0; m < 2; ++m)
#pragma unroll
    for (int n = 0; n < 8; ++n) acc[m][n] = (f32x4){0.f, 0.f, 0.f, 0.f};

  for (int k0 = 0; k0 < K; k0 += 32) {
    int ks = k0 + kg;
    bf16x8 a[2], b[8];
#pragma unroll
    for (int m = 0; m < 2; ++m) {
      int rr = rbase + m * 16 + r16;
      if (rr >= M) rr = M - 1;
      a[m] = *(const bf16x8*)(A + (size_t)rr * K + ks);
    }
#pragma unroll
    for (int n = 0; n < 8; ++n) {
      int cl = n * 16 + r16;
      int byte = (cl * 2 * K + ks * 2) ^ ((cl & 7) << 4);
      b[n] = *(const bf16x8*)((const char*)ws + byte);
    }
#pragma unroll
    for (int m = 0; m < 2; ++m)
#pragma unroll
      for (int n = 0; n < 8; ++n)
        acc[m][n] = __builtin_amdgcn_mfma_f32_16x16x32_bf16(a[m], b[n], acc[m][n], 0, 0, 0);
  }

  int rowoff = (lane >> 4) * 4;
#pragma unroll
  for (int m = 0; m < 2; ++m) {
#pragma unroll
    for (int j = 0; j < 4; ++j) {
      int row = rbase + m * 16 + rowoff + j;
      if (row >= M) continue;
#pragma unroll
      for (int n = 0; n < 8; ++n) {
        int col = colt + n * 16 + r16;
        float v = acc[m][n][j] + bias[col];
        if (relu) v = fmaxf(v, 0.f);
        C[(size_t)row * NC + col] = f2bf(v);
      }
    }
  }
}

template <int K>
__global__ __launch_bounds__(256, 2) void mfma_gemm_lds(
    const ushort* __restrict__ A, const ushort* __restrict__ W,
    const float* __restrict__ bias, ushort* __restrict__ C,
    int M, int NC, int relu) {
  __shared__ ushort ws[128 * K];
  gemm_body<K>(ws, blockIdx.x, blockIdx.y, A, W, bias, C, M, NC, relu);
}

// ---------------- qa2 GEMM fused with global mean pool ----------------------
// Computes relu(A@W^T+b) tile (128 rows x 128 cols), stages in LDS, then
// per-column segmented sum over sorted batch -> atomicAdd into gbuf [G][256].
__global__ __launch_bounds__(256, 2) void qa2_pool(
    const ushort* __restrict__ A, const ushort* __restrict__ W,
    const float* __restrict__ bias, const int* __restrict__ batch,
    float* __restrict__ gbuf, int M) {
  const int K = 128;
  __shared__ ushort ws[128 * 132];  // W stage (32KB linear) then tile[128][132]
  int tid = threadIdx.x;
  int lane = tid & 63;
  int wv = tid >> 6;
  int bx = blockIdx.x, by = blockIdx.y;
  int rbase0 = bx * 128;
  int rbase = rbase0 + wv * 32;
  int colt = by * 128;
  int r16 = lane & 15;
  int kg = (lane >> 4) * 8;

  const char* wt = (const char*)(W + (size_t)colt * K);
#pragma unroll
  for (int i = 0; i < K / 16; ++i) {
    int o = (i * 256 + tid) * 16;
    int col = o / (2 * K);
    int sw = o ^ ((col & 7) << 4);
    *(bf16x8*)((char*)ws + sw) = *(const bf16x8*)(wt + o);
  }
  __syncthreads();

  f32x4 acc[2][8];
#pragma unroll
  for (int m = 0; m < 2; ++m)
#pragma unroll
    for (int n = 0; n < 8; ++n) acc[m][n] = (f32x4){0.f, 0.f, 0.f, 0.f};

  for (int k0 = 0; k0 < K; k0 += 32) {
    int ks = k0 + kg;
    bf16x8 a[2], b[8];
#pragma unroll
    for (int m = 0; m < 2; ++m) {
      int rr = rbase + m * 16 + r16;
      if (rr >= M) rr = M - 1;
      a[m] = *(const bf16x8*)(A + (size_t)rr * K + ks);
    }
#pragma unroll
    for (int n = 0; n < 8; ++n) {
      int cl = n * 16 + r16;
      int byte = (cl * 2 * K + ks * 2) ^ ((cl & 7) << 4);
      b[n] = *(const bf16x8*)((const char*)ws + byte);
    }
#pragma unroll
    for (int m = 0; m < 2; ++m)
#pragma unroll
      for (int n = 0; n < 8; ++n)
        acc[m][n] = __builtin_amdgcn_mfma_f32_16x16x32_bf16(a[m], b[n], acc[m][n], 0, 0, 0);
  }
  __syncthreads();  // all waves done reading W from ws

  // write tile (bias+relu, bf16) into ws as [128][132]
  int rowoff = (lane >> 4) * 4;
#pragma unroll
  for (int m = 0; m < 2; ++m) {
#pragma unroll
    for (int j = 0; j < 4; ++j) {
      int lrow = wv * 32 + m * 16 + rowoff + j;
#pragma unroll
      for (int n = 0; n < 8; ++n) {
        int lcol = n * 16 + r16;
        float v = fmaxf(acc[m][n][j] + bias[colt + lcol], 0.f);
        ws[lrow * 132 + lcol] = f2bf(v);
      }
    }
  }
  __syncthreads();

  // per-column segmented pooled sum (batch sorted); 2 threads/col (row halves)
  int col = tid & 127, half = tid >> 7;
  int r0 = half * 64, r1 = r0 + 64;
  float s = 0.f;
  int curg = -1;
  for (int r = r0; r < r1; ++r) {
    int row = rbase0 + r;
    if (row >= M) break;
    int gg = batch[row];
    if (gg != curg) {
      if (curg >= 0) atomicAdd(gbuf + (size_t)curg * 256 + colt + col, s);
      curg = gg;
      s = 0.f;
    }
    s += bfu(ws[r * 132 + col]);
  }
  if (curg >= 0) atomicAdd(gbuf + (size_t)curg * 256 + colt + col, s);
}

// ---------------- fused: csr_scatter (blocks < NBLKE) ∥ lin1 GEMM ----------
__global__ __launch_bounds__(256, 2) void scatter_lin1(
    const int* __restrict__ src, const int* __restrict__ dst,
    const int* __restrict__ bh, const int* __restrict__ bt, uint* __restrict__ tmp,
    const ushort* __restrict__ feat, const ushort* __restrict__ l1w,
    const float* __restrict__ lin1b, ushort* __restrict__ linx) {
  __shared__ ushort ws[128 * 96];
  int bid = blockIdx.x, t = threadIdx.x;
  if (bid < NBLKE) {
    int* sc = (int*)ws;
    int* cur = sc + 256;
    int v = (t < NBIN) ? bt[t] : 0;
    sc[t] = v;
    __syncthreads();
    for (int off = 1; off < 256; off <<= 1) {
      int u = (t >= off) ? sc[t - off] : 0;
      __syncthreads();
      sc[t] += u;
      __syncthreads();
    }
    if (t < NBIN) cur[t] = (sc[t] - v) + bh[(size_t)t * NBLKE + bid];
    __syncthreads();
    int base = bid * 4096;
#pragma unroll
    for (int i = 0; i < 16; ++i) {
      int idx = base + i * 256 + t;
      if (idx < N_EDGESC) {
        int d = dst[idx];
        uint p = ((uint)d << 16) | (uint)src[idx];
        int pos = atomicAdd(&cur[d >> 8], 1);
        tmp[pos] = p;
      }
    }
  } else {
    gemm_body<96>(ws, bid - NBLKE, 0, feat, l1w, lin1b, linx, N_NODESC, 128, 0);
  }
}

// ---------------- per-bucket counting sort -> elist (ushort) + rp -----------
__global__ __launch_bounds__(256) void csr_bucket_sort(const uint* __restrict__ tmp,
                                                       const int* __restrict__ bt,
                                                       ushort* __restrict__ elist,
                                                       int* __restrict__ rp) {
  __shared__ int sc[256];
  __shared__ int cnt[256];
  int b = blockIdx.x, t = threadIdx.x;
  int v = (t < NBIN) ? bt[t] : 0;
  sc[t] = v;
  __syncthreads();
  for (int off = 1; off < 256; off <<= 1) {
    int u = (t >= off) ? sc[t - off] : 0;
    __syncthreads();
    sc[t] += u;
    __syncthreads();
  }
  int base = (b == 0) ? 0 : sc[b - 1];
  int end = sc[b];
  int total = sc[NBIN - 1];
  __syncthreads();
  cnt[t] = 0;
  __syncthreads();
  for (int i = base + t; i < end; i += 256)
    atomicAdd(&cnt[(tmp[i] >> 16) & 255], 1);
  __syncthreads();
  int cv = cnt[t];
  sc[t] = cv;
  __syncthreads();
  for (int off = 1; off < 256; off <<= 1) {
    int u = (t >= off) ? sc[t - off] : 0;
    __syncthreads();
    sc[t] += u;
    __syncthreads();
  }
  int excl = sc[t] - cv;
  int node = (b << 8) + t;
  if (node < N_NODESC) rp[node] = base + excl;
  if (b == NBIN - 1 && t == 0) rp[N_NODESC] = total;
  cnt[t] = base + excl;  // global cursor
  __syncthreads();
  for (int i = base + t; i < end; i += 256) {
    uint p = tmp[i];
    int pos = atomicAdd(&cnt[(p >> 16) & 255], 1);
    elist[pos] = (ushort)(p & 0xFFFFu);
  }
}

// ---------------- aggregation: h2[n] = 2*linx[n] + sum_{e->n} linx[src] -----
// Row-major [N][128] bf16; wave per node; lane covers cols {2c,2c+1};
// 32 gathers in flight (statically-indexed batch -> registers). (round-9 form)
__global__ __launch_bounds__(256) void aggregate2(const uint* __restrict__ lx,
                                                  const int* __restrict__ rp,
                                                  const ushort* __restrict__ elist,
                                                  uint* __restrict__ h2) {
  int wv = threadIdx.x >> 6, lane = threadIdx.x & 63;
  int n = blockIdx.x * 4 + wv;
  int beg = rp[n], end = rp[n + 1];
  uint su = lx[(size_t)n * 64 + lane];
  float a0 = 2.f * bflo(su), a1 = 2.f * bfhi(su);
  int e = beg;
  for (; e + 32 <= end; e += 32) {
    uint r[32];
#pragma unroll
    for (int i = 0; i < 32; ++i) {
      int s = elist[e + i];
      r[i] = lx[(size_t)s * 64 + lane];
    }
#pragma unroll
    for (int i = 0; i < 32; ++i) { a0 += bflo(r[i]); a1 += bfhi(r[i]); }
  }
  for (; e + 8 <= end; e += 8) {
    uint r[8];
#pragma unroll
    for (int i = 0; i < 8; ++i) {
      int s = elist[e + i];
      r[i] = lx[(size_t)s * 64 + lane];
    }
#pragma unroll
    for (int i = 0; i < 8; ++i) { a0 += bflo(r[i]); a1 += bfhi(r[i]); }
  }
  for (; e < end; ++e) {
    uint r0 = lx[(size_t)elist[e] * 64 + lane];
    a0 += bflo(r0);
    a1 += bfhi(r0);
  }
  h2[(size_t)n * 64 + lane] = (uint)f2bf(a0) | ((uint)f2bf(a1) << 16);
}

// ---------------- per-property heads (8 graphs per block) -------------------
__global__ __launch_bounds__(128) void head_kernel(const float* __restrict__ g,
    const float* __restrict__ cntf,
    const float* __restrict__ w1, const float* __restrict__ b1,
    const float* __restrict__ w2, const float* __restrict__ b2,
    float* __restrict__ out) {
  int p = blockIdx.y;
  int g0 = blockIdx.x * 8;
  int t = threadIdx.x;
  __shared__ float gs[8][256];
  for (int i = t; i < 8 * 256; i += 128) {
    int q = i >> 8;
    gs[q][i & 255] = g[(size_t)(g0 + q) * 256 + (i & 255)] / cntf[g0 + q];
  }
  __syncthreads();
  const float4* w4 = (const float4*)(w1 + ((size_t)p * 128 + t) * 256);
  float bv = b1[p * 128 + t];
  float acc[8];
#pragma unroll
  for (int q = 0; q < 8; ++q) acc[q] = bv;
  for (int d4 = 0; d4 < 64; ++d4) {
    float4 wv = w4[d4];
#pragma unroll
    for (int q = 0; q < 8; ++q) {
      acc[q] += gs[q][d4 * 4 + 0] * wv.x + gs[q][d4 * 4 + 1] * wv.y +
                gs[q][d4 * 4 + 2] * wv.z + gs[q][d4 * 4 + 3] * wv.w;
    }
  }
  float w2v = w2[p * 128 + t];
  __shared__ float red[2][8];
  int wave = t >> 6, lane = t & 63;
#pragma unroll
  for (int q = 0; q < 8; ++q) {
    float v = fmaxf(acc[q], 0.f) * w2v;
    for (int o = 32; o > 0; o >>= 1) v += __shfl_down(v, o, 64);
    if (lane == 0) red[wave][q] = v;
  }
  __syncthreads();
  if (t < 8) out[(size_t)(g0 + t) * 8 + p] = red[0][t] + red[1][t] + b2[p];
}

extern "C" void kernel_launch(void* const* d_in, const int* in_sizes, int n_in,
                              void* d_out, int out_size, void* d_ws, size_t ws_size,
                              hipStream_t stream) {
  const int*   x     = (const int*)d_in[0];
  const int*   ei    = (const int*)d_in[1];
  const int*   batch = (const int*)d_in[2];
  const float* emb24 = (const float*)d_in[3];
  const float* emb72 = (const float*)d_in[4];
  const float* lin1w = (const float*)d_in[5];
  const float* lin1b = (const float*)d_in[6];
  const float* qa1w  = (const float*)d_in[7];
  const float* qa1b  = (const float*)d_in[8];
  const float* lin2w = (const float*)d_in[9];
  const float* lin2b = (const float*)d_in[10];
  const float* qa2w  = (const float*)d_in[11];
  const float* qa2b  = (const float*)d_in[12];
  const float* hw1   = (const float*)d_in[13];
  const float* hb1   = (const float*)d_in[14];
  const float* hw2   = (const float*)d_in[15];
  const float* hb2   = (const float*)d_in[16];
  float* out = (float*)d_out;

  const int* srcv = ei;
  const int* dstv = ei + N_EDGESC;

  char* wsb = (char*)d_ws;
  size_t off = 0;
  auto alloc = [&](size_t b) { char* p = wsb + off; off += (b + 255) & ~(size_t)255; return p; };
  ushort* feat  = (ushort*)alloc((size_t)N_NODESC * 96 * 2);
  ushort* linx  = (ushort*)alloc((size_t)N_NODESC * 128 * 2);   // row-major [N][128]
  ushort* h2    = (ushort*)alloc((size_t)N_NODESC * 128 * 2);   // row-major
  ushort* h     = (ushort*)alloc((size_t)N_NODESC * 256 * 2);   // row-major (qa1 out)
  float*  gbuf  = (float*)alloc((size_t)NGC * 256 * 4);
  float*  cntf  = (float*)alloc((size_t)NGC * 4);
  ushort* qe1   = (ushort*)alloc(256 * 128 * 2);
  ushort* qe2   = (ushort*)alloc(256 * 128 * 2);
  ushort* l1w   = (ushort*)alloc(128 * 96 * 2);
  ushort* l2w   = (ushort*)alloc(128 * 256 * 2);
  int*    rp    = (int*)alloc((size_t)(N_NODESC + 1) * 4);
  ushort* elist = (ushort*)alloc((size_t)N_EDGESC * 2);
  int*    bh    = (int*)alloc((size_t)NBIN * NBLKE * 4);
  int*    bt    = (int*)alloc((size_t)NBIN * 4);
  uint*   tmp   = (uint*)h;  // alias: h not written until qa1 (after CSR done)

  // zero the pooled-sum buffer (gbuf accumulated via atomics)
  hipMemsetAsync(gbuf, 0, (size_t)NGC * 256 * 4, stream);

  // fused prep: weights + features + histogram + graph counts
  megaprep<<<1848, 256, 0, stream>>>(qa1w, qa2w, lin1w, lin2w, qe1, qe2, l1w, l2w,
                                     x, emb24, emb72, feat, dstv, bh, batch, cntf);
  csr_scan_bins<<<NBIN, 64, 0, stream>>>(bh, bt);

  int gm = (N_NODESC + 127) / 128;  // 391

  // scatter ∥ lin1 GEMM (independent)
  scatter_lin1<<<NBLKE + gm, 256, 0, stream>>>(srcv, dstv, bh, bt, tmp,
                                               feat, l1w, lin1b, linx);
  csr_bucket_sort<<<NBIN, 256, 0, stream>>>(tmp, bt, elist, rp);

  // layer 1
  aggregate2<<<N_NODESC / 4, 256, 0, stream>>>((const uint*)linx, rp, elist, (uint*)h2);
  mfma_gemm_lds<128><<<dim3(gm, 2), 256, 0, stream>>>(h2, qe1, qa1b, h, N_NODESC, 256, 1);

  // layer 2
  mfma_gemm_lds<256><<<dim3(gm, 1), 256, 0, stream>>>(h, l2w, lin2b, linx, N_NODESC, 128, 0);
  aggregate2<<<N_NODESC / 4, 256, 0, stream>>>((const uint*)linx, rp, elist, (uint*)h2);
  // qa2 fused with mean-pool (h never materialized for layer 2)
  qa2_pool<<<dim3(gm, 2), 256, 0, stream>>>(h2, qe2, qa2b, batch, gbuf, N_NODESC);

  // heads (divide pooled sums by counts in-kernel)
  head_kernel<<<dim3(NGC / 8, NPC), 128, 0, stream>>>(gbuf, cntf, hw1, hb1, hw2, hb2, out);
}

// Round 14
// 253.327 us; speedup vs baseline: 1.0591x; 1.0591x over previous
//
#include <hip/hip_runtime.h>
#include <hip/hip_bf16.h>

#define N_NODESC 50000
#define N_EDGESC 1600000
#define NGC 1024
#define NPC 8
#define NBIN 196          // dst>>8 buckets (256 nodes each)
#define NBLKE 391         // edge chunks of 4096

typedef __attribute__((ext_vector_type(8))) short bf16x8;
typedef __attribute__((ext_vector_type(4))) float f32x4;

__device__ inline ushort f2bf(float f) {
  union { float f; uint u; } v; v.f = f;
  uint u = v.u;
  u += 0x7FFF + ((u >> 16) & 1);
  return (ushort)(u >> 16);
}
__device__ inline float bflo(uint u) {
  union { uint u; float f; } v; v.u = u << 16; return v.f;
}
__device__ inline float bfhi(uint u) {
  union { uint u; float f; } v; v.u = u & 0xFFFF0000u; return v.f;
}

// ---------------- fused prep: weights + features + edge histogram ----------
__global__ __launch_bounds__(256) void megaprep(
    const float* __restrict__ qa1w, const float* __restrict__ qa2w,
    const float* __restrict__ lin1w, const float* __restrict__ lin2w,
    ushort* __restrict__ qe1, ushort* __restrict__ qe2,
    ushort* __restrict__ l1w, ushort* __restrict__ l2w,
    const int* __restrict__ x, const float* __restrict__ e24,
    const float* __restrict__ e72, ushort* __restrict__ feat,
    const int* __restrict__ dst, int* __restrict__ bh) {
  int bid = blockIdx.x, t = threadIdx.x;
  if (bid < 256) {
    const float* qw = (bid < 128) ? qa1w : qa2w;
    ushort* eff = (bid < 128) ? qe1 : qe2;
    int k = (bid & 127) * 2 + (t >> 7);
    int j = t & 127;
    const float* r = qw + (size_t)k * 256;
    float v;
    if (j < 64) v = r[j] + r[128 + j] + r[192 + j];
    else { int j2 = j - 64; v = r[64 + j2] + r[128 + j2] + 2.0f * r[192 + j2]; }
    eff[(size_t)k * 128 + j] = f2bf(v);
  } else if (bid < 304) {
    int i = (bid - 256) * 256 + t;  // < 12288 = 128*96
    int r = i / 96, c = i - r * 96;
    l1w[i] = (c < 68) ? f2bf(lin1w[(size_t)r * 68 + c]) : (ushort)0;
  } else if (bid < 432) {
    int r = bid - 304;
    l2w[(size_t)r * 256 + t] = f2bf(lin2w[(size_t)r * 256 + t]);
  } else if (bid < 1456) {
    const int stride = 1024 * 256;
    for (int i = (bid - 432) * 256 + t; i < N_NODESC * 96; i += stride) {
      int n = i / 96, tt = i - n * 96;
      float v = 0.f;
      if (tt < 4) v = (float)x[n * 4 + tt];
      else if (tt < 36) { int kk = tt - 4;  int f = kk >> 3, c = kk & 7; v = e24[(x[n * 4 + f] % 24) * 8 + c]; }
      else if (tt < 68) { int kk = tt - 36; int f = kk >> 3, c = kk & 7; v = e72[(x[n * 4 + f] % 72) * 8 + c]; }
      feat[i] = f2bf(v);
    }
  } else {
    __shared__ int hist[NBIN];
    int blk = bid - 1456;
    if (t < NBIN) hist[t] = 0;
    __syncthreads();
    int base = blk * 4096;
#pragma unroll
    for (int i = 0; i < 16; ++i) {
      int idx = base + i * 256 + t;
      if (idx < N_EDGESC) atomicAdd(&hist[dst[idx] >> 8], 1);
    }
    __syncthreads();
    if (t < NBIN) bh[(size_t)t * NBLKE + blk] = hist[t];
  }
}

// ---------------- CSR: per-bin scan ----------------
__global__ __launch_bounds__(64) void csr_scan_bins(int* __restrict__ bh, int* __restrict__ bt) {
  int bin = blockIdx.x;
  int lane = threadIdx.x;
  int carry = 0;
  int* row = bh + (size_t)bin * NBLKE;
  for (int c = 0; c < NBLKE; c += 64) {
    int j = c + lane;
    int v = (j < NBLKE) ? row[j] : 0;
    int incl = v;
#pragma unroll
    for (int off = 1; off < 64; off <<= 1) {
      int u = __shfl_up(incl, off, 64);
      if (lane >= off) incl += u;
    }
    if (j < NBLKE) row[j] = carry + incl - v;
    carry += __shfl(incl, 63, 64);
  }
  if (lane == 0) bt[bin] = carry;
}

// ---------------- shared GEMM body (W staged in swizzled LDS) ---------------
template <int K>
__device__ __forceinline__ void gemm_body(ushort* ws, int bx, int by,
    const ushort* __restrict__ A, const ushort* __restrict__ W,
    const float* __restrict__ bias, ushort* __restrict__ C,
    int M, int NC, int relu) {
  int tid = threadIdx.x;
  int lane = tid & 63;
  int wv = tid >> 6;
  int rbase = bx * 128 + wv * 32;
  int colt = by * 128;
  int r16 = lane & 15;
  int kg = (lane >> 4) * 8;

  const char* wt = (const char*)(W + (size_t)colt * K);
#pragma unroll
  for (int i = 0; i < K / 16; ++i) {
    int o = (i * 256 + tid) * 16;
    int col = o / (2 * K);
    int sw = o ^ ((col & 7) << 4);
    *(bf16x8*)((char*)ws + sw) = *(const bf16x8*)(wt + o);
  }
  __syncthreads();

  f32x4 acc[2][8];
#pragma unroll
  for (int m = 0; m < 2; ++m)
#pragma unroll
    for (int n = 0; n < 8; ++n) acc[m][n] = (f32x4){0.f, 0.f, 0.f, 0.f};

  for (int k0 = 0; k0 < K; k0 += 32) {
    int ks = k0 + kg;
    bf16x8 a[2], b[8];
#pragma unroll
    for (int m = 0; m < 2; ++m) {
      int rr = rbase + m * 16 + r16;
      if (rr >= M) rr = M - 1;
      a[m] = *(const bf16x8*)(A + (size_t)rr * K + ks);
    }
#pragma unroll
    for (int n = 0; n < 8; ++n) {
      int cl = n * 16 + r16;
      int byte = (cl * 2 * K + ks * 2) ^ ((cl & 7) << 4);
      b[n] = *(const bf16x8*)((const char*)ws + byte);
    }
#pragma unroll
    for (int m = 0; m < 2; ++m)
#pragma unroll
      for (int n = 0; n < 8; ++n)
        acc[m][n] = __builtin_amdgcn_mfma_f32_16x16x32_bf16(a[m], b[n], acc[m][n], 0, 0, 0);
  }

  int rowoff = (lane >> 4) * 4;
#pragma unroll
  for (int m = 0; m < 2; ++m) {
#pragma unroll
    for (int j = 0; j < 4; ++j) {
      int row = rbase + m * 16 + rowoff + j;
      if (row >= M) continue;
#pragma unroll
      for (int n = 0; n < 8; ++n) {
        int col = colt + n * 16 + r16;
        float v = acc[m][n][j] + bias[col];
        if (relu) v = fmaxf(v, 0.f);
        C[(size_t)row * NC + col] = f2bf(v);
      }
    }
  }
}

template <int K>
__global__ __launch_bounds__(256, 2) void mfma_gemm_lds(
    const ushort* __restrict__ A, const ushort* __restrict__ W,
    const float* __restrict__ bias, ushort* __restrict__ C,
    int M, int NC, int relu) {
  __shared__ ushort ws[128 * K];
  gemm_body<K>(ws, blockIdx.x, blockIdx.y, A, W, bias, C, M, NC, relu);
}

// ---------------- fused: csr_scatter (blocks < NBLKE) ∥ lin1 GEMM ----------
__global__ __launch_bounds__(256, 2) void scatter_lin1(
    const int* __restrict__ src, const int* __restrict__ dst,
    const int* __restrict__ bh, const int* __restrict__ bt, uint* __restrict__ tmp,
    const ushort* __restrict__ feat, const ushort* __restrict__ l1w,
    const float* __restrict__ lin1b, ushort* __restrict__ linx) {
  __shared__ ushort ws[128 * 96];
  int bid = blockIdx.x, t = threadIdx.x;
  if (bid < NBLKE) {
    int* sc = (int*)ws;
    int* cur = sc + 256;
    int v = (t < NBIN) ? bt[t] : 0;
    sc[t] = v;
    __syncthreads();
    for (int off = 1; off < 256; off <<= 1) {
      int u = (t >= off) ? sc[t - off] : 0;
      __syncthreads();
      sc[t] += u;
      __syncthreads();
    }
    if (t < NBIN) cur[t] = (sc[t] - v) + bh[(size_t)t * NBLKE + bid];
    __syncthreads();
    int base = bid * 4096;
#pragma unroll
    for (int i = 0; i < 16; ++i) {
      int idx = base + i * 256 + t;
      if (idx < N_EDGESC) {
        int d = dst[idx];
        uint p = ((uint)d << 16) | (uint)src[idx];
        int pos = atomicAdd(&cur[d >> 8], 1);
        tmp[pos] = p;
      }
    }
  } else {
    gemm_body<96>(ws, bid - NBLKE, 0, feat, l1w, lin1b, linx, N_NODESC, 128, 0);
  }
}

// ---------------- per-bucket counting sort -> elist (ushort) + rp -----------
__global__ __launch_bounds__(256) void csr_bucket_sort(const uint* __restrict__ tmp,
                                                       const int* __restrict__ bt,
                                                       ushort* __restrict__ elist,
                                                       int* __restrict__ rp) {
  __shared__ int sc[256];
  __shared__ int cnt[256];
  int b = blockIdx.x, t = threadIdx.x;
  int v = (t < NBIN) ? bt[t] : 0;
  sc[t] = v;
  __syncthreads();
  for (int off = 1; off < 256; off <<= 1) {
    int u = (t >= off) ? sc[t - off] : 0;
    __syncthreads();
    sc[t] += u;
    __syncthreads();
  }
  int base = (b == 0) ? 0 : sc[b - 1];
  int end = sc[b];
  int total = sc[NBIN - 1];
  __syncthreads();
  cnt[t] = 0;
  __syncthreads();
  for (int i = base + t; i < end; i += 256)
    atomicAdd(&cnt[(tmp[i] >> 16) & 255], 1);
  __syncthreads();
  int cv = cnt[t];
  sc[t] = cv;
  __syncthreads();
  for (int off = 1; off < 256; off <<= 1) {
    int u = (t >= off) ? sc[t - off] : 0;
    __syncthreads();
    sc[t] += u;
    __syncthreads();
  }
  int excl = sc[t] - cv;
  int node = (b << 8) + t;
  if (node < N_NODESC) rp[node] = base + excl;
  if (b == NBIN - 1 && t == 0) rp[N_NODESC] = total;
  cnt[t] = base + excl;  // global cursor
  __syncthreads();
  for (int i = base + t; i < end; i += 256) {
    uint p = tmp[i];
    int pos = atomicAdd(&cnt[(p >> 16) & 255], 1);
    elist[pos] = (ushort)(p & 0xFFFFu);
  }
}

// ---------------- aggregation: h2[n] = 2*linx[n] + sum_{e->n} linx[src] -----
// uint4 gathers: 16-lane group loads one full 256B row -> 4 edges per
// wave-load instruction, 8 loads (32 edges) in flight. Tail padded via zero
// row N_NODESC. Cross-group shfl_xor reduce; group 0 adds self and writes.
__global__ __launch_bounds__(256) void aggregate4(const uint4* __restrict__ LX,
                                                  const int* __restrict__ rp,
                                                  const ushort* __restrict__ elist,
                                                  uint4* __restrict__ h2) {
  int wv = threadIdx.x >> 6, lane = threadIdx.x & 63;
  int g = lane >> 4, l = lane & 15;
  int n = blockIdx.x * 4 + wv;
  int beg = rp[n], end = rp[n + 1];
  float a0 = 0.f, a1 = 0.f, a2 = 0.f, a3 = 0.f;
  float a4 = 0.f, a5 = 0.f, a6 = 0.f, a7 = 0.f;
  int e = beg;
  for (; e + 32 <= end; e += 32) {
    uint4 r[8];
#pragma unroll
    for (int i = 0; i < 8; ++i) {
      int s = elist[e + i * 4 + g];
      r[i] = LX[(size_t)s * 16 + l];
    }
#pragma unroll
    for (int i = 0; i < 8; ++i) {
      a0 += bflo(r[i].x); a1 += bfhi(r[i].x);
      a2 += bflo(r[i].y); a3 += bfhi(r[i].y);
      a4 += bflo(r[i].z); a5 += bfhi(r[i].z);
      a6 += bflo(r[i].w); a7 += bfhi(r[i].w);
    }
  }
  for (; e < end; e += 4) {
    int idx = e + g;
    int s = (idx < end) ? (int)elist[idx] : N_NODESC;  // zero row
    uint4 r = LX[(size_t)s * 16 + l];
    a0 += bflo(r.x); a1 += bfhi(r.x);
    a2 += bflo(r.y); a3 += bfhi(r.y);
    a4 += bflo(r.z); a5 += bfhi(r.z);
    a6 += bflo(r.w); a7 += bfhi(r.w);
  }
  a0 += __shfl_xor(a0, 16); a0 += __shfl_xor(a0, 32);
  a1 += __shfl_xor(a1, 16); a1 += __shfl_xor(a1, 32);
  a2 += __shfl_xor(a2, 16); a2 += __shfl_xor(a2, 32);
  a3 += __shfl_xor(a3, 16); a3 += __shfl_xor(a3, 32);
  a4 += __shfl_xor(a4, 16); a4 += __shfl_xor(a4, 32);
  a5 += __shfl_xor(a5, 16); a5 += __shfl_xor(a5, 32);
  a6 += __shfl_xor(a6, 16); a6 += __shfl_xor(a6, 32);
  a7 += __shfl_xor(a7, 16); a7 += __shfl_xor(a7, 32);
  if (g == 0) {
    uint4 sv = LX[(size_t)n * 16 + l];
    a0 += 2.f * bflo(sv.x); a1 += 2.f * bfhi(sv.x);
    a2 += 2.f * bflo(sv.y); a3 += 2.f * bfhi(sv.y);
    a4 += 2.f * bflo(sv.z); a5 += 2.f * bfhi(sv.z);
    a6 += 2.f * bflo(sv.w); a7 += 2.f * bfhi(sv.w);
    uint4 w;
    w.x = (uint)f2bf(a0) | ((uint)f2bf(a1) << 16);
    w.y = (uint)f2bf(a2) | ((uint)f2bf(a3) << 16);
    w.z = (uint)f2bf(a4) | ((uint)f2bf(a5) << 16);
    w.w = (uint)f2bf(a6) | ((uint)f2bf(a7) << 16);
    h2[(size_t)n * 16 + l] = w;
  }
}

// ---------------- global mean pool (batch sorted), bf16 input ---------------
__global__ __launch_bounds__(256) void pool2(const uint* __restrict__ h,
                                             const int* __restrict__ batch,
                                             float* __restrict__ g) {
  int gg = blockIdx.x;
  int t = threadIdx.x;
  int j = t & 127, rg = t >> 7;
  int lo = 0, hi = N_NODESC;
  while (lo < hi) { int mid = (lo + hi) >> 1; if (batch[mid] < gg) lo = mid + 1; else hi = mid; }
  int beg = lo;
  hi = N_NODESC;
  while (lo < hi) { int mid = (lo + hi) >> 1; if (batch[mid] < gg + 1) lo = mid + 1; else hi = mid; }
  int end = lo;
  float a0 = 0.f, a1 = 0.f;
  int n = beg + rg;
  for (; n + 2 < end; n += 4) {
    uint u = h[(size_t)n * 128 + j];
    uint u2 = h[(size_t)(n + 2) * 128 + j];
    a0 += bflo(u) + bflo(u2);
    a1 += bfhi(u) + bfhi(u2);
  }
  if (n < end) {
    uint u = h[(size_t)n * 128 + j];
    a0 += bflo(u);
    a1 += bfhi(u);
  }
  __shared__ float s0[128], s1[128];
  if (rg == 1) { s0[j] = a0; s1[j] = a1; }
  __syncthreads();
  if (rg == 0) {
    a0 += s0[j];
    a1 += s1[j];
    float cfac = fmaxf((float)(end - beg), 1.0f);
    g[(size_t)gg * 256 + 2 * j] = a0 / cfac;
    g[(size_t)gg * 256 + 2 * j + 1] = a1 / cfac;
  }
}

// ---------------- per-property heads (8 graphs per block) -------------------
__global__ __launch_bounds__(128) void head_kernel(const float* __restrict__ g,
    const float* __restrict__ w1, const float* __restrict__ b1,
    const float* __restrict__ w2, const float* __restrict__ b2,
    float* __restrict__ out) {
  int p = blockIdx.y;
  int g0 = blockIdx.x * 8;
  int t = threadIdx.x;
  __shared__ float gs[8][256];
  for (int i = t; i < 8 * 256; i += 128)
    gs[i >> 8][i & 255] = g[(size_t)(g0 + (i >> 8)) * 256 + (i & 255)];
  __syncthreads();
  const float4* w4 = (const float4*)(w1 + ((size_t)p * 128 + t) * 256);
  float bv = b1[p * 128 + t];
  float acc[8];
#pragma unroll
  for (int q = 0; q < 8; ++q) acc[q] = bv;
  for (int d4 = 0; d4 < 64; ++d4) {
    float4 wv = w4[d4];
#pragma unroll
    for (int q = 0; q < 8; ++q) {
      acc[q] += gs[q][d4 * 4 + 0] * wv.x + gs[q][d4 * 4 + 1] * wv.y +
                gs[q][d4 * 4 + 2] * wv.z + gs[q][d4 * 4 + 3] * wv.w;
    }
  }
  float w2v = w2[p * 128 + t];
  __shared__ float red[2][8];
  int wave = t >> 6, lane = t & 63;
#pragma unroll
  for (int q = 0; q < 8; ++q) {
    float v = fmaxf(acc[q], 0.f) * w2v;
    for (int o = 32; o > 0; o >>= 1) v += __shfl_down(v, o, 64);
    if (lane == 0) red[wave][q] = v;
  }
  __syncthreads();
  if (t < 8) out[(size_t)(g0 + t) * 8 + p] = red[0][t] + red[1][t] + b2[p];
}

extern "C" void kernel_launch(void* const* d_in, const int* in_sizes, int n_in,
                              void* d_out, int out_size, void* d_ws, size_t ws_size,
                              hipStream_t stream) {
  const int*   x     = (const int*)d_in[0];
  const int*   ei    = (const int*)d_in[1];
  const int*   batch = (const int*)d_in[2];
  const float* emb24 = (const float*)d_in[3];
  const float* emb72 = (const float*)d_in[4];
  const float* lin1w = (const float*)d_in[5];
  const float* lin1b = (const float*)d_in[6];
  const float* qa1w  = (const float*)d_in[7];
  const float* qa1b  = (const float*)d_in[8];
  const float* lin2w = (const float*)d_in[9];
  const float* lin2b = (const float*)d_in[10];
  const float* qa2w  = (const float*)d_in[11];
  const float* qa2b  = (const float*)d_in[12];
  const float* hw1   = (const float*)d_in[13];
  const float* hb1   = (const float*)d_in[14];
  const float* hw2   = (const float*)d_in[15];
  const float* hb2   = (const float*)d_in[16];
  float* out = (float*)d_out;

  const int* srcv = ei;
  const int* dstv = ei + N_EDGESC;

  char* wsb = (char*)d_ws;
  size_t off = 0;
  auto alloc = [&](size_t b) { char* p = wsb + off; off += (b + 255) & ~(size_t)255; return p; };
  ushort* feat  = (ushort*)alloc((size_t)N_NODESC * 96 * 2);
  ushort* linx  = (ushort*)alloc((size_t)(N_NODESC + 1) * 128 * 2);  // +1 zero row
  ushort* h2    = (ushort*)alloc((size_t)N_NODESC * 128 * 2);
  ushort* h     = (ushort*)alloc((size_t)N_NODESC * 256 * 2);
  float*  gbuf  = (float*)alloc((size_t)NGC * 256 * 4);
  ushort* qe1   = (ushort*)alloc(256 * 128 * 2);
  ushort* qe2   = (ushort*)alloc(256 * 128 * 2);
  ushort* l1w   = (ushort*)alloc(128 * 96 * 2);
  ushort* l2w   = (ushort*)alloc(128 * 256 * 2);
  int*    rp    = (int*)alloc((size_t)(N_NODESC + 1) * 4);
  ushort* elist = (ushort*)alloc((size_t)N_EDGESC * 2);
  int*    bh    = (int*)alloc((size_t)NBIN * NBLKE * 4);
  int*    bt    = (int*)alloc((size_t)NBIN * 4);
  uint*   tmp   = (uint*)h;  // alias: h not written until qa1 (after CSR done)

  // zero row N_NODESC of linx (gather pad target)
  hipMemsetAsync(linx + (size_t)N_NODESC * 128, 0, 256, stream);

  // fused prep: weights + features + histogram
  megaprep<<<1847, 256, 0, stream>>>(qa1w, qa2w, lin1w, lin2w, qe1, qe2, l1w, l2w,
                                     x, emb24, emb72, feat, dstv, bh);
  csr_scan_bins<<<NBIN, 64, 0, stream>>>(bh, bt);

  int gm = (N_NODESC + 127) / 128;  // 391

  // scatter ∥ lin1 GEMM (independent)
  scatter_lin1<<<NBLKE + gm, 256, 0, stream>>>(srcv, dstv, bh, bt, tmp,
                                               feat, l1w, lin1b, linx);
  csr_bucket_sort<<<NBIN, 256, 0, stream>>>(tmp, bt, elist, rp);

  // layer 1
  aggregate4<<<N_NODESC / 4, 256, 0, stream>>>((const uint4*)linx, rp, elist, (uint4*)h2);
  mfma_gemm_lds<128><<<dim3(gm, 2), 256, 0, stream>>>(h2, qe1, qa1b, h, N_NODESC, 256, 1);

  // layer 2
  mfma_gemm_lds<256><<<dim3(gm, 1), 256, 0, stream>>>(h, l2w, lin2b, linx, N_NODESC, 128, 0);
  aggregate4<<<N_NODESC / 4, 256, 0, stream>>>((const uint4*)linx, rp, elist, (uint4*)h2);
  mfma_gemm_lds<128><<<dim3(gm, 2), 256, 0, stream>>>(h2, qe2, qa2b, h, N_NODESC, 256, 1);

  // pool + heads
  pool2<<<NGC, 256, 0, stream>>>((const uint*)h, batch, gbuf);
  head_kernel<<<dim3(NGC / 8, NPC), 128, 0, stream>>>(gbuf, hw1, hb1, hw2, hb2, out);
}

// Round 15
// 244.473 us; speedup vs baseline: 1.0975x; 1.0362x over previous
//
#include <hip/hip_runtime.h>
#include <hip/hip_bf16.h>

#define N_NODESC 50000
#define N_EDGESC 1600000
#define NGC 1024
#define NPC 8
#define NBIN 196          // dst>>8 buckets (256 nodes each)
#define NBLKE 391         // edge chunks of 4096

typedef __attribute__((ext_vector_type(8))) short bf16x8;
typedef __attribute__((ext_vector_type(4))) float f32x4;

__device__ inline ushort f2bf(float f) {
  union { float f; uint u; } v; v.f = f;
  uint u = v.u;
  u += 0x7FFF + ((u >> 16) & 1);
  return (ushort)(u >> 16);
}
__device__ inline float bflo(uint u) {
  union { uint u; float f; } v; v.u = u << 16; return v.f;
}
__device__ inline float bfhi(uint u) {
  union { uint u; float f; } v; v.u = u & 0xFFFF0000u; return v.f;
}

// ---------------- fused prep: weights + features + edge histogram ----------
__global__ __launch_bounds__(256) void megaprep(
    const float* __restrict__ qa1w, const float* __restrict__ qa2w,
    const float* __restrict__ lin1w, const float* __restrict__ lin2w,
    ushort* __restrict__ qe1, ushort* __restrict__ qe2,
    ushort* __restrict__ l1w, ushort* __restrict__ l2w,
    const int* __restrict__ x, const float* __restrict__ e24,
    const float* __restrict__ e72, ushort* __restrict__ feat,
    const int* __restrict__ dst, int* __restrict__ bh) {
  int bid = blockIdx.x, t = threadIdx.x;
  if (bid < 256) {
    const float* qw = (bid < 128) ? qa1w : qa2w;
    ushort* eff = (bid < 128) ? qe1 : qe2;
    int k = (bid & 127) * 2 + (t >> 7);
    int j = t & 127;
    const float* r = qw + (size_t)k * 256;
    float v;
    if (j < 64) v = r[j] + r[128 + j] + r[192 + j];
    else { int j2 = j - 64; v = r[64 + j2] + r[128 + j2] + 2.0f * r[192 + j2]; }
    eff[(size_t)k * 128 + j] = f2bf(v);
  } else if (bid < 304) {
    int i = (bid - 256) * 256 + t;  // < 12288 = 128*96
    int r = i / 96, c = i - r * 96;
    l1w[i] = (c < 68) ? f2bf(lin1w[(size_t)r * 68 + c]) : (ushort)0;
  } else if (bid < 432) {
    int r = bid - 304;
    l2w[(size_t)r * 256 + t] = f2bf(lin2w[(size_t)r * 256 + t]);
  } else if (bid < 1456) {
    const int stride = 1024 * 256;
    for (int i = (bid - 432) * 256 + t; i < N_NODESC * 96; i += stride) {
      int n = i / 96, tt = i - n * 96;
      float v = 0.f;
      if (tt < 4) v = (float)x[n * 4 + tt];
      else if (tt < 36) { int kk = tt - 4;  int f = kk >> 3, c = kk & 7; v = e24[(x[n * 4 + f] % 24) * 8 + c]; }
      else if (tt < 68) { int kk = tt - 36; int f = kk >> 3, c = kk & 7; v = e72[(x[n * 4 + f] % 72) * 8 + c]; }
      feat[i] = f2bf(v);
    }
  } else {
    __shared__ int hist[NBIN];
    int blk = bid - 1456;
    if (t < NBIN) hist[t] = 0;
    __syncthreads();
    int base = blk * 4096;
#pragma unroll
    for (int i = 0; i < 16; ++i) {
      int idx = base + i * 256 + t;
      if (idx < N_EDGESC) atomicAdd(&hist[dst[idx] >> 8], 1);
    }
    __syncthreads();
    if (t < NBIN) bh[(size_t)t * NBLKE + blk] = hist[t];
  }
}

// ---------------- CSR: per-bin scan ----------------
__global__ __launch_bounds__(64) void csr_scan_bins(int* __restrict__ bh, int* __restrict__ bt) {
  int bin = blockIdx.x;
  int lane = threadIdx.x;
  int carry = 0;
  int* row = bh + (size_t)bin * NBLKE;
  for (int c = 0; c < NBLKE; c += 64) {
    int j = c + lane;
    int v = (j < NBLKE) ? row[j] : 0;
    int incl = v;
#pragma unroll
    for (int off = 1; off < 64; off <<= 1) {
      int u = __shfl_up(incl, off, 64);
      if (lane >= off) incl += u;
    }
    if (j < NBLKE) row[j] = carry + incl - v;
    carry += __shfl(incl, 63, 64);
  }
  if (lane == 0) bt[bin] = carry;
}

// ---------------- shared GEMM body (W staged in swizzled LDS) ---------------
template <int K>
__device__ __forceinline__ void gemm_body(ushort* ws, int bx, int by,
    const ushort* __restrict__ A, const ushort* __restrict__ W,
    const float* __restrict__ bias, ushort* __restrict__ C,
    int M, int NC, int relu) {
  int tid = threadIdx.x;
  int lane = tid & 63;
  int wv = tid >> 6;
  int rbase = bx * 128 + wv * 32;
  int colt = by * 128;
  int r16 = lane & 15;
  int kg = (lane >> 4) * 8;

  const char* wt = (const char*)(W + (size_t)colt * K);
#pragma unroll
  for (int i = 0; i < K / 16; ++i) {
    int o = (i * 256 + tid) * 16;
    int col = o / (2 * K);
    int sw = o ^ ((col & 7) << 4);
    *(bf16x8*)((char*)ws + sw) = *(const bf16x8*)(wt + o);
  }
  __syncthreads();

  f32x4 acc[2][8];
#pragma unroll
  for (int m = 0; m < 2; ++m)
#pragma unroll
    for (int n = 0; n < 8; ++n) acc[m][n] = (f32x4){0.f, 0.f, 0.f, 0.f};

  for (int k0 = 0; k0 < K; k0 += 32) {
    int ks = k0 + kg;
    bf16x8 a[2], b[8];
#pragma unroll
    for (int m = 0; m < 2; ++m) {
      int rr = rbase + m * 16 + r16;
      if (rr >= M) rr = M - 1;
      a[m] = *(const bf16x8*)(A + (size_t)rr * K + ks);
    }
#pragma unroll
    for (int n = 0; n < 8; ++n) {
      int cl = n * 16 + r16;
      int byte = (cl * 2 * K + ks * 2) ^ ((cl & 7) << 4);
      b[n] = *(const bf16x8*)((const char*)ws + byte);
    }
#pragma unroll
    for (int m = 0; m < 2; ++m)
#pragma unroll
      for (int n = 0; n < 8; ++n)
        acc[m][n] = __builtin_amdgcn_mfma_f32_16x16x32_bf16(a[m], b[n], acc[m][n], 0, 0, 0);
  }

  int rowoff = (lane >> 4) * 4;
#pragma unroll
  for (int m = 0; m < 2; ++m) {
#pragma unroll
    for (int j = 0; j < 4; ++j) {
      int row = rbase + m * 16 + rowoff + j;
      if (row >= M) continue;
#pragma unroll
      for (int n = 0; n < 8; ++n) {
        int col = colt + n * 16 + r16;
        float v = acc[m][n][j] + bias[col];
        if (relu) v = fmaxf(v, 0.f);
        C[(size_t)row * NC + col] = f2bf(v);
      }
    }
  }
}

template <int K>
__global__ __launch_bounds__(256, 2) void mfma_gemm_lds(
    const ushort* __restrict__ A, const ushort* __restrict__ W,
    const float* __restrict__ bias, ushort* __restrict__ C,
    int M, int NC, int relu) {
  __shared__ ushort ws[128 * K];
  gemm_body<K>(ws, blockIdx.x, blockIdx.y, A, W, bias, C, M, NC, relu);
}

// ---------------- fused: csr_scatter (blocks < NBLKE) ∥ lin1 GEMM ----------
__global__ __launch_bounds__(256, 2) void scatter_lin1(
    const int* __restrict__ src, const int* __restrict__ dst,
    const int* __restrict__ bh, const int* __restrict__ bt, uint* __restrict__ tmp,
    const ushort* __restrict__ feat, const ushort* __restrict__ l1w,
    const float* __restrict__ lin1b, ushort* __restrict__ linx) {
  __shared__ ushort ws[128 * 96];
  int bid = blockIdx.x, t = threadIdx.x;
  if (bid < NBLKE) {
    int* sc = (int*)ws;
    int* cur = sc + 256;
    int v = (t < NBIN) ? bt[t] : 0;
    sc[t] = v;
    __syncthreads();
    for (int off = 1; off < 256; off <<= 1) {
      int u = (t >= off) ? sc[t - off] : 0;
      __syncthreads();
      sc[t] += u;
      __syncthreads();
    }
    if (t < NBIN) cur[t] = (sc[t] - v) + bh[(size_t)t * NBLKE + bid];
    __syncthreads();
    int base = bid * 4096;
#pragma unroll
    for (int i = 0; i < 16; ++i) {
      int idx = base + i * 256 + t;
      if (idx < N_EDGESC) {
        int d = dst[idx];
        uint p = ((uint)d << 16) | (uint)src[idx];
        int pos = atomicAdd(&cur[d >> 8], 1);
        tmp[pos] = p;
      }
    }
  } else {
    gemm_body<96>(ws, bid - NBLKE, 0, feat, l1w, lin1b, linx, N_NODESC, 128, 0);
  }
}

// ---------------- per-bucket counting sort -> elist (ushort) + rp -----------
__global__ __launch_bounds__(256) void csr_bucket_sort(const uint* __restrict__ tmp,
                                                       const int* __restrict__ bt,
                                                       ushort* __restrict__ elist,
                                                       int* __restrict__ rp) {
  __shared__ int sc[256];
  __shared__ int cnt[256];
  int b = blockIdx.x, t = threadIdx.x;
  int v = (t < NBIN) ? bt[t] : 0;
  sc[t] = v;
  __syncthreads();
  for (int off = 1; off < 256; off <<= 1) {
    int u = (t >= off) ? sc[t - off] : 0;
    __syncthreads();
    sc[t] += u;
    __syncthreads();
  }
  int base = (b == 0) ? 0 : sc[b - 1];
  int end = sc[b];
  int total = sc[NBIN - 1];
  __syncthreads();
  cnt[t] = 0;
  __syncthreads();
  for (int i = base + t; i < end; i += 256)
    atomicAdd(&cnt[(tmp[i] >> 16) & 255], 1);
  __syncthreads();
  int cv = cnt[t];
  sc[t] = cv;
  __syncthreads();
  for (int off = 1; off < 256; off <<= 1) {
    int u = (t >= off) ? sc[t - off] : 0;
    __syncthreads();
    sc[t] += u;
    __syncthreads();
  }
  int excl = sc[t] - cv;
  int node = (b << 8) + t;
  if (node < N_NODESC) rp[node] = base + excl;
  if (b == NBIN - 1 && t == 0) rp[N_NODESC] = total;
  cnt[t] = base + excl;  // global cursor
  __syncthreads();
  for (int i = base + t; i < end; i += 256) {
    uint p = tmp[i];
    int pos = atomicAdd(&cnt[(p >> 16) & 255], 1);
    elist[pos] = (ushort)(p & 0xFFFFu);
  }
}

// ---------------- aggregation: h2[n] = 2*linx[n] + sum_{e->n} linx[src] -----
// Row-major [N][128] bf16; wave per node; lane covers cols {2c,2c+1};
// 16 gathers in flight (statically-indexed batch -> registers).
// At the L2/L3 random-line service ceiling (~3.2 TB/s): instruction count,
// vector width, layout, and edge order all proven non-levers (rounds 4-14).
__global__ __launch_bounds__(256) void aggregate2(const uint* __restrict__ lx,
                                                  const int* __restrict__ rp,
                                                  const ushort* __restrict__ elist,
                                                  uint* __restrict__ h2) {
  int wv = threadIdx.x >> 6, lane = threadIdx.x & 63;
  int n = blockIdx.x * 4 + wv;
  int beg = rp[n], end = rp[n + 1];
  uint su = lx[(size_t)n * 64 + lane];
  float a0 = 2.f * bflo(su), a1 = 2.f * bfhi(su);
  int e = beg;
  for (; e + 16 <= end; e += 16) {
    uint r[16];
#pragma unroll
    for (int i = 0; i < 16; ++i) {
      int s = elist[e + i];
      r[i] = lx[(size_t)s * 64 + lane];
    }
#pragma unroll
    for (int i = 0; i < 16; ++i) { a0 += bflo(r[i]); a1 += bfhi(r[i]); }
  }
  for (; e + 4 <= end; e += 4) {
    uint r0 = lx[(size_t)elist[e] * 64 + lane];
    uint r1 = lx[(size_t)elist[e + 1] * 64 + lane];
    uint r2 = lx[(size_t)elist[e + 2] * 64 + lane];
    uint r3 = lx[(size_t)elist[e + 3] * 64 + lane];
    a0 += bflo(r0) + bflo(r1) + bflo(r2) + bflo(r3);
    a1 += bfhi(r0) + bfhi(r1) + bfhi(r2) + bfhi(r3);
  }
  for (; e < end; ++e) {
    uint r0 = lx[(size_t)elist[e] * 64 + lane];
    a0 += bflo(r0);
    a1 += bfhi(r0);
  }
  h2[(size_t)n * 64 + lane] = (uint)f2bf(a0) | ((uint)f2bf(a1) << 16);
}

// ---------------- global mean pool (batch sorted), bf16 input ---------------
__global__ __launch_bounds__(256) void pool2(const uint* __restrict__ h,
                                             const int* __restrict__ batch,
                                             float* __restrict__ g) {
  int gg = blockIdx.x;
  int t = threadIdx.x;
  int j = t & 127, rg = t >> 7;
  int lo = 0, hi = N_NODESC;
  while (lo < hi) { int mid = (lo + hi) >> 1; if (batch[mid] < gg) lo = mid + 1; else hi = mid; }
  int beg = lo;
  hi = N_NODESC;
  while (lo < hi) { int mid = (lo + hi) >> 1; if (batch[mid] < gg + 1) lo = mid + 1; else hi = mid; }
  int end = lo;
  float a0 = 0.f, a1 = 0.f;
  int n = beg + rg;
  for (; n + 2 < end; n += 4) {
    uint u = h[(size_t)n * 128 + j];
    uint u2 = h[(size_t)(n + 2) * 128 + j];
    a0 += bflo(u) + bflo(u2);
    a1 += bfhi(u) + bfhi(u2);
  }
  if (n < end) {
    uint u = h[(size_t)n * 128 + j];
    a0 += bflo(u);
    a1 += bfhi(u);
  }
  __shared__ float s0[128], s1[128];
  if (rg == 1) { s0[j] = a0; s1[j] = a1; }
  __syncthreads();
  if (rg == 0) {
    a0 += s0[j];
    a1 += s1[j];
    float cfac = fmaxf((float)(end - beg), 1.0f);
    g[(size_t)gg * 256 + 2 * j] = a0 / cfac;
    g[(size_t)gg * 256 + 2 * j + 1] = a1 / cfac;
  }
}

// ---------------- per-property heads (8 graphs per block) -------------------
__global__ __launch_bounds__(128) void head_kernel(const float* __restrict__ g,
    const float* __restrict__ w1, const float* __restrict__ b1,
    const float* __restrict__ w2, const float* __restrict__ b2,
    float* __restrict__ out) {
  int p = blockIdx.y;
  int g0 = blockIdx.x * 8;
  int t = threadIdx.x;
  __shared__ float gs[8][256];
  for (int i = t; i < 8 * 256; i += 128)
    gs[i >> 8][i & 255] = g[(size_t)(g0 + (i >> 8)) * 256 + (i & 255)];
  __syncthreads();
  const float4* w4 = (const float4*)(w1 + ((size_t)p * 128 + t) * 256);
  float bv = b1[p * 128 + t];
  float acc[8];
#pragma unroll
  for (int q = 0; q < 8; ++q) acc[q] = bv;
  for (int d4 = 0; d4 < 64; ++d4) {
    float4 wv = w4[d4];
#pragma unroll
    for (int q = 0; q < 8; ++q) {
      acc[q] += gs[q][d4 * 4 + 0] * wv.x + gs[q][d4 * 4 + 1] * wv.y +
                gs[q][d4 * 4 + 2] * wv.z + gs[q][d4 * 4 + 3] * wv.w;
    }
  }
  float w2v = w2[p * 128 + t];
  __shared__ float red[2][8];
  int wave = t >> 6, lane = t & 63;
#pragma unroll
  for (int q = 0; q < 8; ++q) {
    float v = fmaxf(acc[q], 0.f) * w2v;
    for (int o = 32; o > 0; o >>= 1) v += __shfl_down(v, o, 64);
    if (lane == 0) red[wave][q] = v;
  }
  __syncthreads();
  if (t < 8) out[(size_t)(g0 + t) * 8 + p] = red[0][t] + red[1][t] + b2[p];
}

extern "C" void kernel_launch(void* const* d_in, const int* in_sizes, int n_in,
                              void* d_out, int out_size, void* d_ws, size_t ws_size,
                              hipStream_t stream) {
  const int*   x     = (const int*)d_in[0];
  const int*   ei    = (const int*)d_in[1];
  const int*   batch = (const int*)d_in[2];
  const float* emb24 = (const float*)d_in[3];
  const float* emb72 = (const float*)d_in[4];
  const float* lin1w = (const float*)d_in[5];
  const float* lin1b = (const float*)d_in[6];
  const float* qa1w  = (const float*)d_in[7];
  const float* qa1b  = (const float*)d_in[8];
  const float* lin2w = (const float*)d_in[9];
  const float* lin2b = (const float*)d_in[10];
  const float* qa2w  = (const float*)d_in[11];
  const float* qa2b  = (const float*)d_in[12];
  const float* hw1   = (const float*)d_in[13];
  const float* hb1   = (const float*)d_in[14];
  const float* hw2   = (const float*)d_in[15];
  const float* hb2   = (const float*)d_in[16];
  float* out = (float*)d_out;

  const int* srcv = ei;
  const int* dstv = ei + N_EDGESC;

  char* wsb = (char*)d_ws;
  size_t off = 0;
  auto alloc = [&](size_t b) { char* p = wsb + off; off += (b + 255) & ~(size_t)255; return p; };
  ushort* feat  = (ushort*)alloc((size_t)N_NODESC * 96 * 2);
  ushort* linx  = (ushort*)alloc((size_t)N_NODESC * 128 * 2);   // row-major [N][128]
  ushort* h2    = (ushort*)alloc((size_t)N_NODESC * 128 * 2);   // row-major
  ushort* h     = (ushort*)alloc((size_t)N_NODESC * 256 * 2);   // row-major
  float*  gbuf  = (float*)alloc((size_t)NGC * 256 * 4);
  ushort* qe1   = (ushort*)alloc(256 * 128 * 2);
  ushort* qe2   = (ushort*)alloc(256 * 128 * 2);
  ushort* l1w   = (ushort*)alloc(128 * 96 * 2);
  ushort* l2w   = (ushort*)alloc(128 * 256 * 2);
  int*    rp    = (int*)alloc((size_t)(N_NODESC + 1) * 4);
  ushort* elist = (ushort*)alloc((size_t)N_EDGESC * 2);
  int*    bh    = (int*)alloc((size_t)NBIN * NBLKE * 4);
  int*    bt    = (int*)alloc((size_t)NBIN * 4);
  uint*   tmp   = (uint*)h;  // alias: h not written until qa1 (after CSR done)

  // fused prep: weights + features + histogram
  megaprep<<<1847, 256, 0, stream>>>(qa1w, qa2w, lin1w, lin2w, qe1, qe2, l1w, l2w,
                                     x, emb24, emb72, feat, dstv, bh);
  csr_scan_bins<<<NBIN, 64, 0, stream>>>(bh, bt);

  int gm = (N_NODESC + 127) / 128;  // 391

  // scatter ∥ lin1 GEMM (independent)
  scatter_lin1<<<NBLKE + gm, 256, 0, stream>>>(srcv, dstv, bh, bt, tmp,
                                               feat, l1w, lin1b, linx);
  csr_bucket_sort<<<NBIN, 256, 0, stream>>>(tmp, bt, elist, rp);

  // layer 1
  aggregate2<<<N_NODESC / 4, 256, 0, stream>>>((const uint*)linx, rp, elist, (uint*)h2);
  mfma_gemm_lds<128><<<dim3(gm, 2), 256, 0, stream>>>(h2, qe1, qa1b, h, N_NODESC, 256, 1);

  // layer 2
  mfma_gemm_lds<256><<<dim3(gm, 1), 256, 0, stream>>>(h, l2w, lin2b, linx, N_NODESC, 128, 0);
  aggregate2<<<N_NODESC / 4, 256, 0, stream>>>((const uint*)linx, rp, elist, (uint*)h2);
  mfma_gemm_lds<128><<<dim3(gm, 2), 256, 0, stream>>>(h2, qe2, qa2b, h, N_NODESC, 256, 1);

  // pool + heads
  pool2<<<NGC, 256, 0, stream>>>((const uint*)h, batch, gbuf);
  head_kernel<<<dim3(NGC / 8, NPC), 128, 0, stream>>>(gbuf, hw1, hb1, hw2, hb2, out);
}